// Round 10
// baseline (640.544 us; speedup 1.0000x reference)
//
#include <hip/hip_runtime.h>
#include <stdint.h>

typedef __attribute__((ext_vector_type(8))) short short8;
typedef __attribute__((ext_vector_type(4))) float f32x4;

#define DEVI __device__ __forceinline__

// float -> bf16 bits, round-to-nearest-even
DEVI unsigned short f2b(float f) {
  union { float f; unsigned u; } v; v.f = f;
  return (unsigned short)((v.u + 0x7fffu + ((v.u >> 16) & 1u)) >> 16);
}

// async global->LDS, 16B per lane; LDS dest must be wave-uniform base + lane*16
#define GLD16(g, s) __builtin_amdgcn_global_load_lds( \
    (const __attribute__((address_space(1))) void*)(g), \
    (__attribute__((address_space(3))) void*)(s), 16, 0, 0)

// ---------------------------------------------------------------------------
// NT GEMM body: C[M][N] = A[M][K] * B[N][K]^T, bf16 in, f32 accum.
// 128x128 tile, BK=32, 4 waves, 16x16x32 MFMA.
// R8: 2-buffer LDS ring (32 KB) + __launch_bounds__(256,4) -> 4 blocks/CU
// (occupancy play: R4/R6/R7 proved pipeline depth & swizzle are null at these
// shapes; the untouched axis is TLP). 1-deep prefetch issued AFTER barrier.
// Safety: wave W's ds_reads of buf (kt+1)&1 (read at iter kt-1) retired before
// W entered barrier kt; stage(kt+1) is issued post-barrier -> WAR-safe.
// vmcnt(0) at loop top drains the single stage issued one compute-phase ago.
//
// LDS bank swizzle (kept from R7 baseline, harmless): slot (row,s) holds
// k-chunk s ^ ((row>>1)&3); staging permutes global source, read XORs kch.
//
// EPI: 0 = store bf16; 1 = store f32 * scale; 2 = store f32 + resid
template <int EPI>
DEVI void gemm_body(const unsigned short* __restrict__ A,
                    const unsigned short* __restrict__ B, void* __restrict__ Cv,
                    const float* __restrict__ resid, int bm, int bn, int K, int lda,
                    int ldb, int ldc, float scale, unsigned short* lds) {
  const int tid = threadIdx.x;
  const int wave = tid >> 6, lane = tid & 63;
  const int wm = wave >> 1, wn = wave & 1;

  f32x4 acc[4][4] = {};

  // staging geometry: each wave stages 32 rows (2x16) of each tile, 16B/lane/load
  const int r0 = wave * 32 + (lane >> 2);
  const int c0 = (((lane & 3) ^ ((lane >> 3) & 3)) * 8);  // swizzled source slot
  const unsigned short* ga = A + (size_t)(bm * 128 + r0) * lda + c0;
  const unsigned short* gb = B + (size_t)(bn * 128 + r0) * ldb + c0;
  const size_t stepA16 = (size_t)16 * lda;
  const size_t stepB16 = (size_t)16 * ldb;
  unsigned short* sbase = lds + wave * 1024 + lane * 8;  // per-lane LDS stage addr

  const int rowa = wm * 64 + (lane & 15);
  const int rowb = wn * 64 + (lane & 15);
  const int kch = (((lane >> 4) ^ ((lane >> 1) & 3)) * 8);  // swizzled read slot

  const int nK = K >> 5;

  auto stage = [&](int kt, int buf) {
    const unsigned short* gA = ga + kt * 32;
    const unsigned short* gB = gb + kt * 32;
    unsigned short* dA = sbase + buf * 8192;
    unsigned short* dB = dA + 4096;
    GLD16(gA, dA);
    GLD16(gA + stepA16, dA + 512);
    GLD16(gB, dB);
    GLD16(gB + stepB16, dB + 512);
  };

  stage(0, 0);
  for (int kt = 0; kt < nK; ++kt) {
    asm volatile("s_waitcnt vmcnt(0)" ::: "memory");  // stage(kt) resident
    __builtin_amdgcn_s_barrier();  // tile kt resident for ALL waves
    asm volatile("" ::: "memory"); // fence: no ds_read hoist above barrier
    if (kt + 1 < nK) stage(kt + 1, (kt + 1) & 1);  // hides under compute below
    const unsigned short* Ab = lds + (kt & 1) * 8192;
    const unsigned short* Bb = Ab + 4096;
    short8 af[4], bq[4];
#pragma unroll
    for (int mi = 0; mi < 4; ++mi)
      af[mi] = *reinterpret_cast<const short8*>(&Ab[(rowa + mi * 16) * 32 + kch]);
#pragma unroll
    for (int ni = 0; ni < 4; ++ni)
      bq[ni] = *reinterpret_cast<const short8*>(&Bb[(rowb + ni * 16) * 32 + kch]);
#pragma unroll
    for (int mi = 0; mi < 4; ++mi)
#pragma unroll
      for (int ni = 0; ni < 4; ++ni)
        acc[mi][ni] = __builtin_amdgcn_mfma_f32_16x16x32_bf16(af[mi], bq[ni], acc[mi][ni], 0, 0, 0);
  }

  // epilogue: C/D layout col = lane&15, row = (lane>>4)*4 + reg  [m89-verified]
  const int cc = lane & 15, rr = (lane >> 4) * 4;
  const int rbase = bm * 128 + wm * 64, cbase = bn * 128 + wn * 64;
  if constexpr (EPI == 0) {
    unsigned short* C = (unsigned short*)Cv;
#pragma unroll
    for (int mi = 0; mi < 4; ++mi)
#pragma unroll
      for (int ni = 0; ni < 4; ++ni)
#pragma unroll
        for (int r = 0; r < 4; ++r)
          C[(size_t)(rbase + mi * 16 + rr + r) * ldc + (cbase + ni * 16 + cc)] =
              f2b(acc[mi][ni][r]);
  } else if constexpr (EPI == 1) {
    float* C = (float*)Cv;
#pragma unroll
    for (int mi = 0; mi < 4; ++mi)
#pragma unroll
      for (int ni = 0; ni < 4; ++ni)
#pragma unroll
        for (int r = 0; r < 4; ++r)
          C[(size_t)(rbase + mi * 16 + rr + r) * ldc + (cbase + ni * 16 + cc)] =
              acc[mi][ni][r] * scale;
  } else {
    float* C = (float*)Cv;
#pragma unroll
    for (int mi = 0; mi < 4; ++mi)
#pragma unroll
      for (int ni = 0; ni < 4; ++ni)
#pragma unroll
        for (int r = 0; r < 4; ++r) {
          const size_t idx = (size_t)(rbase + mi * 16 + rr + r) * ldc + (cbase + ni * 16 + cc);
          C[idx] = acc[mi][ni][r] + resid[idx];
        }
  }
}

// ---------------------------------------------------------------------------
// PREP (fused): pool(x1)->x1fT bf16 | transpose(x2)->x2fT bf16 | W->bf16
// 1-D grid: [0,3072) pool, [3072,6144) x2t, [6144,6720) wconv. block 256.
__global__ __launch_bounds__(256) void prep_kernel(
    const float* __restrict__ x1, const float* __restrict__ x2,
    const float* __restrict__ Wq, const float* __restrict__ Wk,
    const float* __restrict__ Wv, unsigned short* __restrict__ x1fT,
    unsigned short* __restrict__ x2fT, unsigned short* __restrict__ Wqb,
    unsigned short* __restrict__ Wkb, unsigned short* __restrict__ Wvb) {
  const int tid = threadIdx.x;
  __shared__ float tile[64][33];
  int id = blockIdx.x;
  if (id < 3072) {
    // ---- pool: 4x4 mean of x1[b][c][128][128] -> x1fT[(b*1024+n)][c] bf16
    const int c0 = (id % 12) * 64;
    const int ho = (id / 12) % 32;
    const int b = id / 384;
    const int ci = tid >> 5, wo = tid & 31;
#pragma unroll 2
    for (int cc = 0; cc < 8; ++cc) {
      const int c = c0 + cc * 8 + ci;
      const float* base = x1 + ((size_t)(b * 768 + c) * 128 + ho * 4) * 128 + wo * 4;
      float s = 0.f;
#pragma unroll
      for (int i = 0; i < 4; ++i) {
        f32x4 v = *reinterpret_cast<const f32x4*>(base + (size_t)i * 128);
        s += v[0] + v[1] + v[2] + v[3];
      }
      tile[cc * 8 + ci][wo] = s * 0.0625f;
    }
    __syncthreads();
    const int wo2 = tid >> 3, cg = tid & 7;
    uint4 pk;
    pk.x = (unsigned)f2b(tile[cg * 8 + 0][wo2]) | ((unsigned)f2b(tile[cg * 8 + 1][wo2]) << 16);
    pk.y = (unsigned)f2b(tile[cg * 8 + 2][wo2]) | ((unsigned)f2b(tile[cg * 8 + 3][wo2]) << 16);
    pk.z = (unsigned)f2b(tile[cg * 8 + 4][wo2]) | ((unsigned)f2b(tile[cg * 8 + 5][wo2]) << 16);
    pk.w = (unsigned)f2b(tile[cg * 8 + 6][wo2]) | ((unsigned)f2b(tile[cg * 8 + 7][wo2]) << 16);
    *reinterpret_cast<uint4*>(&x1fT[(size_t)(b * 1024 + ho * 32 + wo2) * 768 + c0 + cg * 8]) = pk;
  } else if (id < 6144) {
    // ---- x2 transpose: x2[b][c][n] -> x2fT[(b*1024+n)][c] bf16
    id -= 3072;
    const int ct = id % 12;
    const int nt = (id / 12) % 32;
    const int b = id / 384;
    {
      const int nl = tid & 31, cb = tid >> 5;
#pragma unroll
      for (int p = 0; p < 8; ++p) {
        const int cl = p * 8 + cb;
        tile[cl][nl] = x2[(size_t)(b * 768 + ct * 64 + cl) * 1024 + nt * 32 + nl];
      }
    }
    __syncthreads();
    {
      const int c2 = tid & 63, nb = tid >> 6;
#pragma unroll
      for (int p = 0; p < 8; ++p) {
        const int nl = p * 4 + nb;
        x2fT[(size_t)(b * 1024 + nt * 32 + nl) * 768 + ct * 64 + c2] = f2b(tile[c2][nl]);
      }
    }
  } else {
    // ---- weight convert f32->bf16, 16B stores
    const int i = (id - 6144) * 256 + tid;
    f32x4 a = reinterpret_cast<const f32x4*>(Wq)[i];
    f32x4 b = reinterpret_cast<const f32x4*>(Wk)[i];
    f32x4 c = reinterpret_cast<const f32x4*>(Wv)[i];
    uint2 oa, ob, oc;
    oa.x = (unsigned)f2b(a[0]) | ((unsigned)f2b(a[1]) << 16);
    oa.y = (unsigned)f2b(a[2]) | ((unsigned)f2b(a[3]) << 16);
    ob.x = (unsigned)f2b(b[0]) | ((unsigned)f2b(b[1]) << 16);
    ob.y = (unsigned)f2b(b[2]) | ((unsigned)f2b(b[3]) << 16);
    oc.x = (unsigned)f2b(c[0]) | ((unsigned)f2b(c[1]) << 16);
    oc.y = (unsigned)f2b(c[2]) | ((unsigned)f2b(c[3]) << 16);
    reinterpret_cast<uint2*>(Wqb)[i] = oa;
    reinterpret_cast<uint2*>(Wkb)[i] = ob;
    reinterpret_cast<uint2*>(Wvb)[i] = oc;
  }
}

// ---------------------------------------------------------------------------
// QKV (fused, one dispatch = 1152 blocks, 4 blocks/CU):
//  [0,384):   k  = Wk * x1f    -> kb  [768][8192]
//  [384,768): q  = Wq * x2f    -> qb  [768][8192]
//  [768,1152):vT = x1fT * Wv^T -> vTb [8192][768]
__global__ __launch_bounds__(256, 4) void qkv_kernel(
    const unsigned short* __restrict__ Wkb, const unsigned short* __restrict__ Wqb,
    const unsigned short* __restrict__ Wvb, const unsigned short* __restrict__ x1fT,
    const unsigned short* __restrict__ x2fT, unsigned short* __restrict__ kb,
    unsigned short* __restrict__ qb, unsigned short* __restrict__ vTb) {
  __shared__ unsigned short lds[2 * 8192];  // 2 ring buffers x (A 8KB + B 8KB)
  int id = blockIdx.x;
  if (id < 384) {
    gemm_body<0>(Wkb, x1fT, kb, nullptr, id >> 6, id & 63, 768, 768, 768, 8192, 1.f, lds);
  } else if (id < 768) {
    id -= 384;
    gemm_body<0>(Wqb, x2fT, qb, nullptr, id >> 6, id & 63, 768, 768, 768, 8192, 1.f, lds);
  } else {
    id -= 768;
    gemm_body<0>(x1fT, Wvb, vTb, nullptr, id / 6, id % 6, 768, 768, 768, 768, 1.f, lds);
  }
}

// attn partials: p[kh][b] = q[b][:, kh*512:+512] * k[b][:, kh*512:+512]^T / 32
// grid (6,6,16): z = kh*8 + b. Split-K=2 -> 576 blocks, 16 iters each.
__global__ __launch_bounds__(256, 4) void attn_kernel(const unsigned short* __restrict__ qb,
                                                      const unsigned short* __restrict__ kb,
                                                      float* __restrict__ attnp) {
  __shared__ unsigned short lds[2 * 8192];
  const int z = blockIdx.z;
  const int b = z & 7, kh = z >> 3;
  gemm_body<1>(qb + b * 1024 + kh * 512, kb + b * 1024 + kh * 512,
               attnp + (size_t)z * 589824, nullptr, blockIdx.y, blockIdx.x, 512, 8192,
               8192, 768, 1.f / 32.f, lds);
}

// out[b] = attn[b] * v[b] + x2[b]   [768][1024] f32 -> d_out
__global__ __launch_bounds__(256, 4) void out_kernel(const unsigned short* __restrict__ attnb,
                                                     const unsigned short* __restrict__ vTb,
                                                     float* __restrict__ out,
                                                     const float* __restrict__ x2) {
  __shared__ unsigned short lds[2 * 8192];
  const int bz = blockIdx.z;
  gemm_body<2>(attnb + (size_t)bz * 589824, vTb + (size_t)bz * 786432,
               out + (size_t)bz * 786432, x2 + (size_t)bz * 786432, blockIdx.y, blockIdx.x,
               768, 768, 768, 1024, 1.f, lds);
}

// ---------------------------------------------------------------------------
// Row softmax over summed split-K partials: S = p0 + p1 (already scaled),
// [6144 rows][768] f32 -> P bf16, one wave per row.
__global__ __launch_bounds__(256) void softmax_kernel(const float* __restrict__ S,
                                                      unsigned short* __restrict__ P) {
  const int row = blockIdx.x * 4 + (threadIdx.x >> 6);
  const int lane = threadIdx.x & 63;
  const float* r0 = S + (size_t)row * 768;
  const float* r1 = r0 + (size_t)8 * 589824;  // second K-half partial
  f32x4 v[3];
  float mx = -1e30f;
#pragma unroll
  for (int i = 0; i < 3; ++i) {
    f32x4 a = *reinterpret_cast<const f32x4*>(r0 + (i * 64 + lane) * 4);
    f32x4 b = *reinterpret_cast<const f32x4*>(r1 + (i * 64 + lane) * 4);
    v[i][0] = a[0] + b[0]; v[i][1] = a[1] + b[1];
    v[i][2] = a[2] + b[2]; v[i][3] = a[3] + b[3];
    mx = fmaxf(fmaxf(fmaxf(v[i][0], v[i][1]), fmaxf(v[i][2], v[i][3])), mx);
  }
#pragma unroll
  for (int off = 32; off > 0; off >>= 1) mx = fmaxf(mx, __shfl_xor(mx, off));
  float sum = 0.f;
#pragma unroll
  for (int i = 0; i < 3; ++i)
#pragma unroll
    for (int j = 0; j < 4; ++j) {
      v[i][j] = __expf(v[i][j] - mx);
      sum += v[i][j];
    }
#pragma unroll
  for (int off = 32; off > 0; off >>= 1) sum += __shfl_xor(sum, off);
  const float inv = 1.f / sum;
  unsigned short* p = P + (size_t)row * 768;
#pragma unroll
  for (int i = 0; i < 3; ++i) {
    uint2 o;
    o.x = (unsigned)f2b(v[i][0] * inv) | ((unsigned)f2b(v[i][1] * inv) << 16);
    o.y = (unsigned)f2b(v[i][2] * inv) | ((unsigned)f2b(v[i][3] * inv) << 16);
    *reinterpret_cast<uint2*>(p + (i * 64 + lane) * 4) = o;
  }
}

// ---------------------------------------------------------------------------
extern "C" void kernel_launch(void* const* d_in, const int* in_sizes, int n_in,
                              void* d_out, int out_size, void* d_ws, size_t ws_size,
                              hipStream_t stream) {
  const float* x1 = (const float*)d_in[0];  // [8][768][128][128]
  const float* x2 = (const float*)d_in[1];  // [8][768][32][32]
  const float* Wq = (const float*)d_in[2];  // [768][768]
  const float* Wk = (const float*)d_in[3];
  const float* Wv = (const float*)d_in[4];
  float* out = (float*)d_out;  // [8][768][32][32]

  char* ws = (char*)d_ws;
  size_t off = 0;
  auto alloc = [&](size_t bytes) {
    char* p = ws + off;
    off += (bytes + 255) & ~(size_t)255;
    return p;
  };
  unsigned short* x1fT = (unsigned short*)alloc((size_t)8192 * 768 * 2);  // [b*n][c1]
  unsigned short* x2fT = (unsigned short*)alloc((size_t)8192 * 768 * 2);  // [b*n][c2]
  unsigned short* Wqb = (unsigned short*)alloc((size_t)589824 * 2);
  unsigned short* Wkb = (unsigned short*)alloc((size_t)589824 * 2);
  unsigned short* Wvb = (unsigned short*)alloc((size_t)589824 * 2);
  unsigned short* qb = (unsigned short*)alloc((size_t)768 * 8192 * 2);   // [c2][b*n]
  unsigned short* kb = (unsigned short*)alloc((size_t)768 * 8192 * 2);   // [c1][b*n]
  unsigned short* vTb = (unsigned short*)alloc((size_t)8192 * 768 * 2);  // [b*n][c1]
  float* attnp = (float*)alloc((size_t)2 * 8 * 768 * 768 * 4);           // [kh][b][c2][c1]
  unsigned short* attnb = x2fT;  // overlay: x2fT dead after q-GEMM

  // 1. prep: pool x1, transpose x2, convert weights (all independent, one dispatch)
  prep_kernel<<<dim3(6720), 256, 0, stream>>>(x1, x2, Wq, Wk, Wv, x1fT, x2fT, Wqb, Wkb, Wvb);
  // 2. q/k/vT GEMMs in one dispatch (1152 blocks, 4/CU)
  qkv_kernel<<<dim3(1152), 256, 0, stream>>>(Wkb, Wqb, Wvb, x1fT, x2fT, kb, qb, vTb);
  // 3. attn partials (split-K=2, 576 blocks)
  attn_kernel<<<dim3(6, 6, 16), 256, 0, stream>>>(qb, kb, attnp);
  // 4. softmax over summed partials -> bf16 (into dead x2fT)
  softmax_kernel<<<dim3(1536), 256, 0, stream>>>(attnp, attnb);
  // 5. out = attn v + x2
  out_kernel<<<dim3(8, 6, 8), 256, 0, stream>>>(attnb, vTb, out, x2);
}